// Round 14
// baseline (259.845 us; speedup 1.0000x reference)
//
#include <hip/hip_runtime.h>

#define N_NODES 50000
#define N_EDGES 800000
#define N_GRAPHS 512
#define HID 128
#define OUT_DIM 10
#define NBUK 256
#define NPB 196            // nodes per bucket (256*196 = 50176 >= 50000)
#define BUK_STRIDE 4096    // mean 3125, sigma ~56; fixed input -> safe
#define HPAD 136           // LDS row pitch in shorts (272B: 16B-aligned, 2-way banks)
#define CONVX_BLOCKS 6250  // (N_NODES*HID/4)/256
#define CONVW_BLOCKS 512   // (8*128*128)/256

typedef short bf16x8 __attribute__((ext_vector_type(8)));
typedef float f32x4 __attribute__((ext_vector_type(4)));

__device__ __forceinline__ unsigned short bf16_rn(float f) {
    unsigned u = __float_as_uint(f);
    u += 0x7FFFu + ((u >> 16) & 1u);
    return (unsigned short)(u >> 16);
}
__device__ __forceinline__ float bf16_f(unsigned short h) {
    return __uint_as_float(((unsigned)h) << 16);
}

// ---------------------------------------------------------------------------
// merged prep: conv_x (blocks 0..6249), conv_weights (blocks 6250..6761),
// and bukCnt zeroing (first weights block).
// ---------------------------------------------------------------------------
__global__ __launch_bounds__(256) void prep_kernel(
    const float* __restrict__ x, unsigned short* __restrict__ xh,
    const float* __restrict__ W1, const float* __restrict__ W2,
    unsigned short* __restrict__ Wth, int* __restrict__ bukCnt)
{
    int b = blockIdx.x;
    if (b < CONVX_BLOCKS) {
        int t = b * 256 + threadIdx.x;
        const float4 v = reinterpret_cast<const float4*>(x)[t];
        ushort4 h;
        h.x = bf16_rn(v.x);
        h.y = bf16_rn(v.y);
        h.z = bf16_rn(v.z);
        h.w = bf16_rn(v.w);
        reinterpret_cast<ushort4*>(xh)[t] = h;
    } else {
        int bb = b - CONVX_BLOCKS;
        if (bb == 0) bukCnt[threadIdx.x] = 0;
        int t = bb * 256 + threadIdx.x;
        int mat = t >> 14;
        int idx = t & 16383;
        int n = idx >> 7;
        int k = idx & 127;
        const float* W = (mat < 4) ? (W1 + (size_t)mat * HID * HID)
                                   : (W2 + (size_t)(mat - 4) * HID * HID);
        Wth[t] = bf16_rn(W[k * HID + n]);
    }
}

// ---------------------------------------------------------------------------
// pass 1: bin packed edges (dst<<16 | src) into 256 coarse buckets.
// ---------------------------------------------------------------------------
__global__ __launch_bounds__(256) void bin_kernel(
    const int* __restrict__ src, const int* __restrict__ dst,
    int* __restrict__ bukCnt, unsigned int* __restrict__ bucketData)
{
    __shared__ int cnt[NBUK];
    __shared__ int base[NBUK];
    int t = threadIdx.x;
    cnt[t] = 0;
    __syncthreads();
    const int per = N_EDGES / 256;        // 3125
    const int e0 = blockIdx.x * per;
    for (int i = t; i < per; i += 256)
        atomicAdd(&cnt[dst[e0 + i] / NPB], 1);
    __syncthreads();
    base[t] = atomicAdd(&bukCnt[t], cnt[t]);
    cnt[t] = 0;
    __syncthreads();
    for (int i = t; i < per; i += 256) {
        int e = e0 + i;
        int s = src[e], d = dst[e];
        int b = d / NPB;
        int pos = base[b] + atomicAdd(&cnt[b], 1);
        bucketData[(size_t)b * BUK_STRIDE + pos] = ((unsigned)d << 16) | (unsigned)s;
    }
}

// ---------------------------------------------------------------------------
// pass 2: one block per bucket. LDS degree hist + local scan -> rowptr + csr.
// ---------------------------------------------------------------------------
__global__ __launch_bounds__(256) void build_kernel(
    const int* __restrict__ bukCnt, const unsigned int* __restrict__ bucketData,
    int* __restrict__ rowptr, int* __restrict__ csr)
{
    __shared__ int sc[NBUK];
    __shared__ int lcnt[NBUK];
    __shared__ int lofs[NBUK];
    int t = threadIdx.x;

    sc[t] = bukCnt[t];
    __syncthreads();
    for (int off = 1; off < NBUK; off <<= 1) {
        int v = (t >= off) ? sc[t - off] : 0;
        __syncthreads();
        sc[t] += v;
        __syncthreads();
    }
    const int bk = blockIdx.x;
    const int bukBase = (bk == 0) ? 0 : sc[bk - 1];
    const int myCnt = bukCnt[bk];
    const int n0 = bk * NPB;
    const int nn = (N_NODES - n0 < NPB) ? (N_NODES - n0) : NPB;
    const unsigned int* data = bucketData + (size_t)bk * BUK_STRIDE;

    lcnt[t] = 0;
    __syncthreads();
    for (int i = t; i < myCnt; i += 256)
        atomicAdd(&lcnt[(int)(data[i] >> 16) - n0], 1);
    __syncthreads();
    lofs[t] = lcnt[t];
    __syncthreads();
    for (int off = 1; off < NBUK; off <<= 1) {
        int v = (t >= off) ? lofs[t - off] : 0;
        __syncthreads();
        lofs[t] += v;
        __syncthreads();
    }
    int excl = lofs[t] - lcnt[t];
    __syncthreads();
    lofs[t] = excl;
    if (t < nn) rowptr[n0 + t] = bukBase + excl;
    if (bk == NBUK - 1 && t == 0) rowptr[N_NODES] = N_EDGES;
    lcnt[t] = 0;
    __syncthreads();
    for (int i = t; i < myCnt; i += 256) {
        unsigned int pk = data[i];
        int dl = (int)(pk >> 16) - n0;
        int pos = lofs[dl] + atomicAdd(&lcnt[dl], 1);
        csr[bukBase + pos] = (int)(pk & 0xFFFFu);
    }
}

// ---------------------------------------------------------------------------
// fused GIN layer v2: gather-aggregate 128 rows into LDS (sH), then
// out = BN(relu( relu(h0@W1 + b1) @ W2 + b2 )), all bf16-hi state.
// LDS = sH ONLY (34.8 KB) -> 4 blocks/CU; W1/W2 fragments loaded straight
// from global (32 KB each = L1-resident after first wave). Phase-1 swapped;
// h1 overwrites h0 in sH (own-wave stripe, per-wave lgkmcnt ordering —
// single __syncthreads after the gather is the only barrier).
// ---------------------------------------------------------------------------
__global__ __launch_bounds__(256, 4) void layer_fused(
    const unsigned short* __restrict__ Xc,
    const int* __restrict__ rowptr, const int* __restrict__ csr_src,
    const float* __restrict__ epsp,
    const unsigned short* __restrict__ W1t, const float* __restrict__ b1,
    const unsigned short* __restrict__ W2t, const float* __restrict__ b2,
    const float* __restrict__ bn_g, const float* __restrict__ bn_b,
    const float* __restrict__ bn_m, const float* __restrict__ bn_v,
    unsigned short* __restrict__ Oh)
{
    __shared__ __align__(16) unsigned short sH[128 * HPAD];  // 34.8 KB

    const int tid  = threadIdx.x;
    const int wave = tid >> 6;
    const int lane = tid & 63;
    const int lr   = lane & 15;
    const int lg   = lane >> 4;
    const int mW   = wave * 32;
    const int m0   = blockIdx.x * 128;

    // ---- gather phase: this block's 128 rows -> sH (bf16) ----
    {
        const int grp = tid >> 4;
        const int ln  = tid & 15;
        const float ev = 1.0f + epsp[0];
        for (int it = 0; it < 8; ++it) {
            const int row = it * 16 + grp;
            const int n = m0 + row;
            int beg = 0, end = 0;
            if (n < N_NODES) { beg = rowptr[n]; end = rowptr[n + 1]; }
            float a[8];
            #pragma unroll
            for (int j = 0; j < 8; ++j) a[j] = 0.f;
            for (int e0 = beg; e0 < end; e0 += 16) {
                const int cnt = end - e0;
                int sl = (e0 + ln < end) ? csr_src[e0 + ln] : 0;
                bf16x8 v[16];
                #pragma unroll
                for (int u = 0; u < 8; ++u) {
                    int s = __shfl(sl, u, 16);
                    v[u] = *reinterpret_cast<const bf16x8*>(Xc + (size_t)s * HID + ln * 8);
                }
                #pragma unroll
                for (int u = 0; u < 8; ++u) {
                    float m = (u < cnt) ? 1.f : 0.f;
                    #pragma unroll
                    for (int j = 0; j < 8; ++j)
                        a[j] = fmaf(m, bf16_f((unsigned short)v[u][j]), a[j]);
                }
                if (cnt > 8) {
                    #pragma unroll
                    for (int u = 8; u < 16; ++u) {
                        int s = __shfl(sl, u, 16);
                        v[u] = *reinterpret_cast<const bf16x8*>(Xc + (size_t)s * HID + ln * 8);
                    }
                    #pragma unroll
                    for (int u = 8; u < 16; ++u) {
                        float m = (u < cnt) ? 1.f : 0.f;
                        #pragma unroll
                        for (int j = 0; j < 8; ++j)
                            a[j] = fmaf(m, bf16_f((unsigned short)v[u][j]), a[j]);
                    }
                }
            }
            const int nc = (n < N_NODES) ? n : (N_NODES - 1);
            bf16x8 sh = *reinterpret_cast<const bf16x8*>(Xc + (size_t)nc * HID + ln * 8);
            bf16x8 o;
            #pragma unroll
            for (int j = 0; j < 8; ++j)
                o[j] = (short)bf16_rn(fmaf(bf16_f((unsigned short)sh[j]), ev, a[j]));
            *reinterpret_cast<bf16x8*>(sH + row * HPAD + ln * 8) = o;
        }
    }
    __syncthreads();   // all h0 rows in sH

    f32x4 acc[2][8];
    #pragma unroll
    for (int i = 0; i < 2; ++i)
        #pragma unroll
        for (int j = 0; j < 8; ++j) acc[i][j] = (f32x4){0.f, 0.f, 0.f, 0.f};

    const size_t wbase = (size_t)lr * HID + lg * 8;

    // ---- phase 1 (swapped): lane -> h1[m0+mW+mt*16+lr][nt*16+lg*4+reg] ----
    #pragma unroll
    for (int ks = 0; ks < 4; ++ks) {
        const int ko = ks * 32;
        bf16x8 bh0 = *reinterpret_cast<const bf16x8*>(sH + (mW + lr) * HPAD + ko + lg * 8);
        bf16x8 bh1 = *reinterpret_cast<const bf16x8*>(sH + (mW + 16 + lr) * HPAD + ko + lg * 8);
        #pragma unroll
        for (int nt = 0; nt < 8; ++nt) {
            bf16x8 w = *reinterpret_cast<const bf16x8*>(
                W1t + wbase + (size_t)nt * 16 * HID + ko);
            acc[0][nt] = __builtin_amdgcn_mfma_f32_16x16x32_bf16(w, bh0, acc[0][nt], 0, 0, 0);
            acc[1][nt] = __builtin_amdgcn_mfma_f32_16x16x32_bf16(w, bh1, acc[1][nt], 0, 0, 0);
        }
    }

    // epilogue 1: relu(+b1) -> bf16 -> sH (own-wave 32-row stripe)
    #pragma unroll
    for (int nt = 0; nt < 8; ++nt) {
        const float4 bs = *reinterpret_cast<const float4*>(b1 + nt * 16 + lg * 4);
        #pragma unroll
        for (int mt = 0; mt < 2; ++mt) {
            ushort4 hi;
            hi.x = bf16_rn(fmaxf(acc[mt][nt][0] + bs.x, 0.f));
            hi.y = bf16_rn(fmaxf(acc[mt][nt][1] + bs.y, 0.f));
            hi.z = bf16_rn(fmaxf(acc[mt][nt][2] + bs.z, 0.f));
            hi.w = bf16_rn(fmaxf(acc[mt][nt][3] + bs.w, 0.f));
            *reinterpret_cast<ushort4*>(
                sH + (mW + mt * 16 + lr) * HPAD + nt * 16 + lg * 4) = hi;
        }
    }
    // no barrier needed: phase-2 reads only this wave's own stripe,
    // ordered by per-wave lgkmcnt on LDS ops.

    // ---- phase 2 (normal): A = h1 from sH (own stripe), B = W2 from global ----
    #pragma unroll
    for (int i = 0; i < 2; ++i)
        #pragma unroll
        for (int j = 0; j < 8; ++j) acc[i][j] = (f32x4){0.f, 0.f, 0.f, 0.f};

    #pragma unroll
    for (int ks = 0; ks < 4; ++ks) {
        const int ko = ks * 32;
        const int la0 = (mW + lr) * HPAD + ko + lg * 8;
        const int la1 = (mW + 16 + lr) * HPAD + ko + lg * 8;
        bf16x8 xh0 = *reinterpret_cast<const bf16x8*>(sH + la0);
        bf16x8 xh1 = *reinterpret_cast<const bf16x8*>(sH + la1);
        #pragma unroll
        for (int nf = 0; nf < 8; ++nf) {
            bf16x8 w = *reinterpret_cast<const bf16x8*>(
                W2t + wbase + (size_t)nf * 16 * HID + ko);
            acc[0][nf] = __builtin_amdgcn_mfma_f32_16x16x32_bf16(xh0, w, acc[0][nf], 0, 0, 0);
            acc[1][nf] = __builtin_amdgcn_mfma_f32_16x16x32_bf16(xh1, w, acc[1][nf], 0, 0, 0);
        }
    }

    // epilogue 2: relu(+b2) -> BN -> bf16
    float bs[8], gg[8], bb[8], mm[8], vv[8];
    #pragma unroll
    for (int nf = 0; nf < 8; ++nf) {
        int c = nf * 16 + lr;
        bs[nf] = b2[c];
        gg[nf] = bn_g[c]; bb[nf] = bn_b[c]; mm[nf] = bn_m[c];
        vv[nf] = rsqrtf(bn_v[c] + 1e-5f);
    }
    #pragma unroll
    for (int mr = 0; mr < 2; ++mr) {
        #pragma unroll
        for (int j = 0; j < 4; ++j) {
            int r = m0 + mW + mr * 16 + lg * 4 + j;
            if (r >= N_NODES) continue;
            #pragma unroll
            for (int nf = 0; nf < 8; ++nf) {
                int c = nf * 16 + lr;
                float v = fmaxf(acc[mr][nf][j] + bs[nf], 0.f);
                v = gg[nf] * (v - mm[nf]) * vv[nf] + bb[nf];
                Oh[(size_t)r * HID + c] = bf16_rn(v);
            }
        }
    }
}

// ---------------------------------------------------------------------------
// fused mean-pool + head: one block per graph.
// ---------------------------------------------------------------------------
__device__ __forceinline__ int lbound(const int* __restrict__ a, int n, int key)
{
    int lo = 0, hi = n;
    while (lo < hi) { int mid = (lo + hi) >> 1; if (a[mid] < key) lo = mid + 1; else hi = mid; }
    return lo;
}

__global__ __launch_bounds__(256) void pool_head_kernel(
    const unsigned short* __restrict__ xh, const int* __restrict__ batch,
    const float* __restrict__ w1, const float* __restrict__ b1,
    const float* __restrict__ w2, const float* __restrict__ b2,
    float* __restrict__ out)
{
    __shared__ float s[16][HID];
    __shared__ float p[HID];
    __shared__ float hh[HID];
    __shared__ float lgits[OUT_DIM];
    int g = blockIdx.x;
    int lo = lbound(batch, N_NODES, g);
    int hi = lbound(batch, N_NODES, g + 1);
    int grp = threadIdx.x >> 4, lane = threadIdx.x & 15;

    float a[8];
    #pragma unroll
    for (int j = 0; j < 8; ++j) a[j] = 0.f;
    for (int n = lo + grp; n < hi; n += 16) {
        bf16x8 v = *reinterpret_cast<const bf16x8*>(xh + (size_t)n * HID + lane * 8);
        #pragma unroll
        for (int j = 0; j < 8; ++j) a[j] += bf16_f((unsigned short)v[j]);
    }
    #pragma unroll
    for (int j = 0; j < 8; ++j) s[grp][lane * 8 + j] = a[j];
    __syncthreads();
    if (threadIdx.x < HID) {
        int c = threadIdx.x;
        float sum = 0.f;
        #pragma unroll
        for (int k = 0; k < 16; ++k) sum += s[k][c];
        float cnt = (float)(hi - lo);
        if (cnt < 1.f) cnt = 1.f;
        p[c] = sum / cnt;
    }
    __syncthreads();

    int j = threadIdx.x;
    if (j < HID) {
        float acc = b1[j];
        #pragma unroll 8
        for (int k = 0; k < HID; ++k) acc = fmaf(p[k], w1[k * HID + j], acc);
        hh[j] = fmaxf(acc, 0.f);
    }
    __syncthreads();

    if (j < OUT_DIM) {
        float acc = b2[j];
        #pragma unroll 8
        for (int k = 0; k < HID; ++k) acc = fmaf(hh[k], w2[k * OUT_DIM + j], acc);
        lgits[j] = acc;
    }
    __syncthreads();

    if (j == 0) {
        float mx = lgits[0];
        for (int o = 1; o < OUT_DIM; ++o) mx = fmaxf(mx, lgits[o]);
        float sum = 0.f;
        for (int o = 0; o < OUT_DIM; ++o) sum += expf(lgits[o] - mx);
        float lse = mx + logf(sum);
        for (int o = 0; o < OUT_DIM; ++o) out[g * OUT_DIM + o] = lgits[o] - lse;
    }
}

// ---------------------------------------------------------------------------
extern "C" void kernel_launch(void* const* d_in, const int* in_sizes, int n_in,
                              void* d_out, int out_size, void* d_ws, size_t ws_size,
                              hipStream_t stream)
{
    const float* x     = (const float*)d_in[0];
    const int*   ei    = (const int*)d_in[1];
    const int*   batch = (const int*)d_in[2];
    const float* W1    = (const float*)d_in[3];
    const float* b1    = (const float*)d_in[4];
    const float* W2    = (const float*)d_in[5];
    const float* b2    = (const float*)d_in[6];
    const float* bng   = (const float*)d_in[7];
    const float* bnb   = (const float*)d_in[8];
    const float* bnm   = (const float*)d_in[9];
    const float* bnv   = (const float*)d_in[10];
    const float* epsg  = (const float*)d_in[11];
    const float* l1w   = (const float*)d_in[12];
    const float* l1b   = (const float*)d_in[13];
    const float* l2w   = (const float*)d_in[14];
    const float* l2b   = (const float*)d_in[15];
    float* out = (float*)d_out;

    const int* src = ei;
    const int* dst = ei + N_EDGES;

    const size_t NF = (size_t)N_NODES * HID;     // 6.4M
    unsigned char* p = (unsigned char*)d_ws;
    unsigned short* xhA = (unsigned short*)p; p += NF * 2;
    unsigned short* xhB = (unsigned short*)p; p += NF * 2;
    unsigned short* Wth = (unsigned short*)p; p += (size_t)8 * HID * HID * 2;
    int* rowptr = (int*)p;                p += (size_t)(N_NODES + 1) * 4;
    int* bukCnt = (int*)p;                p += NBUK * 4;
    unsigned int* bucketData = (unsigned int*)p; p += (size_t)NBUK * BUK_STRIDE * 4;
    int* csr    = (int*)p;

    // ---- prep (once per call): conv_x + conv_weights + bukCnt zero ----
    prep_kernel<<<CONVX_BLOCKS + CONVW_BLOCKS, 256, 0, stream>>>(
        x, xhA, W1, W2, Wth, bukCnt);
    bin_kernel<<<NBUK, 256, 0, stream>>>(src, dst, bukCnt, bucketData);
    build_kernel<<<NBUK, 256, 0, stream>>>(bukCnt, bucketData, rowptr, csr);

    // ---- 4 fused GIN layers ----
    const int layerBlocks = (N_NODES + 127) / 128;   // 391

    unsigned short* cur = xhA;
    unsigned short* nxt = xhB;
    for (int l = 0; l < 4; ++l) {
        layer_fused<<<layerBlocks, 256, 0, stream>>>(
            cur, rowptr, csr, epsg + l,
            Wth + (size_t)l * HID * HID, b1 + l * HID,
            Wth + (size_t)(4 + l) * HID * HID, b2 + l * HID,
            bng + l * HID, bnb + l * HID, bnm + l * HID, bnv + l * HID,
            nxt);
        unsigned short* t = cur; cur = nxt; nxt = t;
    }

    // ---- fused pool + head ----
    pool_head_kernel<<<N_GRAPHS, 256, 0, stream>>>(
        cur, batch, l1w, l1b, l2w, l2b, out);
}

// Round 15
// 213.218 us; speedup vs baseline: 1.2187x; 1.2187x over previous
//
#include <hip/hip_runtime.h>

#define N_NODES 50000
#define N_EDGES 800000
#define N_GRAPHS 512
#define HID 128
#define OUT_DIM 10
#define NBUK 256
#define NPB 196            // nodes per bucket (256*196 = 50176 >= 50000)
#define BUK_STRIDE 4096    // mean 3125, sigma ~56; fixed input -> safe
#define HPAD 136           // LDS row pitch in shorts (272B: 16B-aligned, 2-way banks)
#define CONVX_BLOCKS 6250  // (N_NODES*HID/4)/256
#define CONVW_BLOCKS 512   // (8*128*128)/256

typedef short bf16x8 __attribute__((ext_vector_type(8)));
typedef float f32x4 __attribute__((ext_vector_type(4)));

__device__ __forceinline__ unsigned short bf16_rn(float f) {
    unsigned u = __float_as_uint(f);
    u += 0x7FFFu + ((u >> 16) & 1u);
    return (unsigned short)(u >> 16);
}
__device__ __forceinline__ float bf16_f(unsigned short h) {
    return __uint_as_float(((unsigned)h) << 16);
}

// ---------------------------------------------------------------------------
// merged prep: conv_x (blocks 0..6249), conv_weights (blocks 6250..6761),
// and bukCnt zeroing (first weights block).
// ---------------------------------------------------------------------------
__global__ __launch_bounds__(256) void prep_kernel(
    const float* __restrict__ x, unsigned short* __restrict__ xh,
    const float* __restrict__ W1, const float* __restrict__ W2,
    unsigned short* __restrict__ Wth, int* __restrict__ bukCnt)
{
    int b = blockIdx.x;
    if (b < CONVX_BLOCKS) {
        int t = b * 256 + threadIdx.x;
        const float4 v = reinterpret_cast<const float4*>(x)[t];
        ushort4 h;
        h.x = bf16_rn(v.x);
        h.y = bf16_rn(v.y);
        h.z = bf16_rn(v.z);
        h.w = bf16_rn(v.w);
        reinterpret_cast<ushort4*>(xh)[t] = h;
    } else {
        int bb = b - CONVX_BLOCKS;
        if (bb == 0) bukCnt[threadIdx.x] = 0;
        int t = bb * 256 + threadIdx.x;
        int mat = t >> 14;
        int idx = t & 16383;
        int n = idx >> 7;
        int k = idx & 127;
        const float* W = (mat < 4) ? (W1 + (size_t)mat * HID * HID)
                                   : (W2 + (size_t)(mat - 4) * HID * HID);
        Wth[t] = bf16_rn(W[k * HID + n]);
    }
}

// ---------------------------------------------------------------------------
// pass 1: bin packed edges (dst<<16 | src) into 256 coarse buckets.
// ---------------------------------------------------------------------------
__global__ __launch_bounds__(256) void bin_kernel(
    const int* __restrict__ src, const int* __restrict__ dst,
    int* __restrict__ bukCnt, unsigned int* __restrict__ bucketData)
{
    __shared__ int cnt[NBUK];
    __shared__ int base[NBUK];
    int t = threadIdx.x;
    cnt[t] = 0;
    __syncthreads();
    const int per = N_EDGES / 256;        // 3125
    const int e0 = blockIdx.x * per;
    for (int i = t; i < per; i += 256)
        atomicAdd(&cnt[dst[e0 + i] / NPB], 1);
    __syncthreads();
    base[t] = atomicAdd(&bukCnt[t], cnt[t]);
    cnt[t] = 0;
    __syncthreads();
    for (int i = t; i < per; i += 256) {
        int e = e0 + i;
        int s = src[e], d = dst[e];
        int b = d / NPB;
        int pos = base[b] + atomicAdd(&cnt[b], 1);
        bucketData[(size_t)b * BUK_STRIDE + pos] = ((unsigned)d << 16) | (unsigned)s;
    }
}

// ---------------------------------------------------------------------------
// pass 2: one block per bucket. LDS degree hist + local scan -> rowptr + csr.
// ---------------------------------------------------------------------------
__global__ __launch_bounds__(256) void build_kernel(
    const int* __restrict__ bukCnt, const unsigned int* __restrict__ bucketData,
    int* __restrict__ rowptr, int* __restrict__ csr)
{
    __shared__ int sc[NBUK];
    __shared__ int lcnt[NBUK];
    __shared__ int lofs[NBUK];
    int t = threadIdx.x;

    sc[t] = bukCnt[t];
    __syncthreads();
    for (int off = 1; off < NBUK; off <<= 1) {
        int v = (t >= off) ? sc[t - off] : 0;
        __syncthreads();
        sc[t] += v;
        __syncthreads();
    }
    const int bk = blockIdx.x;
    const int bukBase = (bk == 0) ? 0 : sc[bk - 1];
    const int myCnt = bukCnt[bk];
    const int n0 = bk * NPB;
    const int nn = (N_NODES - n0 < NPB) ? (N_NODES - n0) : NPB;
    const unsigned int* data = bucketData + (size_t)bk * BUK_STRIDE;

    lcnt[t] = 0;
    __syncthreads();
    for (int i = t; i < myCnt; i += 256)
        atomicAdd(&lcnt[(int)(data[i] >> 16) - n0], 1);
    __syncthreads();
    lofs[t] = lcnt[t];
    __syncthreads();
    for (int off = 1; off < NBUK; off <<= 1) {
        int v = (t >= off) ? lofs[t - off] : 0;
        __syncthreads();
        lofs[t] += v;
        __syncthreads();
    }
    int excl = lofs[t] - lcnt[t];
    __syncthreads();
    lofs[t] = excl;
    if (t < nn) rowptr[n0 + t] = bukBase + excl;
    if (bk == NBUK - 1 && t == 0) rowptr[N_NODES] = N_EDGES;
    lcnt[t] = 0;
    __syncthreads();
    for (int i = t; i < myCnt; i += 256) {
        unsigned int pk = data[i];
        int dl = (int)(pk >> 16) - n0;
        int pos = lofs[dl] + atomicAdd(&lcnt[dl], 1);
        csr[bukBase + pos] = (int)(pk & 0xFFFFu);
    }
}

// ---------------------------------------------------------------------------
// aggregate by gather: o[n] = (1+eps)*x[n] + sum x[src], all bf16-hi state.
// 16 lanes per node, bf16x8 (16B) per lane. NO serial tail: full-width
// load blocks with OOB indices clamped to row 0 (L1-hot) and fp-masked
// accumulation -> all gathers in a chunk issue back-to-back.
// ---------------------------------------------------------------------------
__global__ __launch_bounds__(256) void aggregate_kernel(
    const unsigned short* __restrict__ xh,
    const int* __restrict__ rowptr, const int* __restrict__ csr_src,
    const float* __restrict__ epsp,
    unsigned short* __restrict__ oh)
{
    int n = blockIdx.x * 16 + (threadIdx.x >> 4);
    if (n >= N_NODES) return;
    int lane = threadIdx.x & 15;
    int beg = rowptr[n], end = rowptr[n + 1];

    float a[8];
    #pragma unroll
    for (int j = 0; j < 8; ++j) a[j] = 0.f;

    for (int e0 = beg; e0 < end; e0 += 16) {
        const int cnt = end - e0;                       // >= 1
        int sl = (e0 + lane < end) ? csr_src[e0 + lane] : 0;   // OOB -> row 0

        bf16x8 v[16];
        #pragma unroll
        for (int u = 0; u < 8; ++u) {
            int s = __shfl(sl, u, 16);
            v[u] = *reinterpret_cast<const bf16x8*>(xh + (size_t)s * HID + lane * 8);
        }
        #pragma unroll
        for (int u = 0; u < 8; ++u) {
            float m = (u < cnt) ? 1.f : 0.f;
            #pragma unroll
            for (int j = 0; j < 8; ++j)
                a[j] = fmaf(m, bf16_f((unsigned short)v[u][j]), a[j]);
        }
        if (cnt > 8) {
            #pragma unroll
            for (int u = 8; u < 16; ++u) {
                int s = __shfl(sl, u, 16);
                v[u] = *reinterpret_cast<const bf16x8*>(xh + (size_t)s * HID + lane * 8);
            }
            #pragma unroll
            for (int u = 8; u < 16; ++u) {
                float m = (u < cnt) ? 1.f : 0.f;
                #pragma unroll
                for (int j = 0; j < 8; ++j)
                    a[j] = fmaf(m, bf16_f((unsigned short)v[u][j]), a[j]);
            }
        }
    }
    bf16x8 sh = *reinterpret_cast<const bf16x8*>(xh + (size_t)n * HID + lane * 8);
    float ev = 1.0f + epsp[0];
    bf16x8 o;
    #pragma unroll
    for (int j = 0; j < 8; ++j)
        o[j] = (short)bf16_rn(fmaf(bf16_f((unsigned short)sh[j]), ev, a[j]));
    *reinterpret_cast<bf16x8*>(oh + (size_t)n * HID + lane * 8) = o;
}

// ---------------------------------------------------------------------------
// fused MLP: out = BN(relu( relu(h0@W1 + b1) @ W2 + b2 ))  (all bf16-hi state)
// W1 staged in LDS, W2 re-staged into the SAME buffer between phases.
// Phase-1 operand-swapped; h1 kept bf16-hi in LDS. 64 MFMA/phase/wave.
// ---------------------------------------------------------------------------
__global__ __launch_bounds__(256, 2) void mlp_fused(
    const unsigned short* __restrict__ Ah,
    const unsigned short* __restrict__ W1t, const float* __restrict__ b1,
    const unsigned short* __restrict__ W2t, const float* __restrict__ b2,
    const float* __restrict__ bn_g, const float* __restrict__ bn_b,
    const float* __restrict__ bn_m, const float* __restrict__ bn_v,
    unsigned short* __restrict__ Oh)
{
    __shared__ __align__(16) unsigned short sW[128 * HPAD];  // 34.8 KB
    __shared__ __align__(16) unsigned short sH[128 * HPAD];  // 34.8 KB

    const int tid  = threadIdx.x;
    const int wave = tid >> 6;
    const int lane = tid & 63;
    const int lr   = lane & 15;
    const int lg   = lane >> 4;
    const int mW   = wave * 32;
    const int m0   = blockIdx.x * 128 + mW;

    // prefetch A-frags (h0 hi rows r0, r1; 4 k-slices each)
    const int r0 = m0 + lr;
    const int r1 = m0 + 16 + lr;
    const size_t a0 = (size_t)(r0 < N_NODES ? r0 : N_NODES - 1) * HID + lg * 8;
    const size_t a1 = (size_t)(r1 < N_NODES ? r1 : N_NODES - 1) * HID + lg * 8;
    bf16x8 ah0[4], ah1[4];
    #pragma unroll
    for (int ks = 0; ks < 4; ++ks) {
        ah0[ks] = *reinterpret_cast<const bf16x8*>(Ah + a0 + ks * 32);
        ah1[ks] = *reinterpret_cast<const bf16x8*>(Ah + a1 + ks * 32);
    }

    // stage W1 (2048 x 16B, coalesced)
    #pragma unroll
    for (int i = 0; i < 8; ++i) {
        int g = tid + i * 256;
        *reinterpret_cast<bf16x8*>(sW + (g >> 4) * HPAD + (g & 15) * 8) =
            *reinterpret_cast<const bf16x8*>(W1t + g * 8);
    }
    __syncthreads();

    f32x4 acc[2][8];
    #pragma unroll
    for (int i = 0; i < 2; ++i)
        #pragma unroll
        for (int j = 0; j < 8; ++j) acc[i][j] = (f32x4){0.f, 0.f, 0.f, 0.f};

    // ---- phase 1 (swapped): lane -> h1[m0+mt*16+lr][nt*16+lg*4+reg] ----
    #pragma unroll
    for (int ks = 0; ks < 4; ++ks) {
        #pragma unroll
        for (int nt = 0; nt < 8; ++nt) {
            bf16x8 w = *reinterpret_cast<const bf16x8*>(
                sW + (nt * 16 + lr) * HPAD + ks * 32 + lg * 8);
            acc[0][nt] = __builtin_amdgcn_mfma_f32_16x16x32_bf16(w, ah0[ks], acc[0][nt], 0, 0, 0);
            acc[1][nt] = __builtin_amdgcn_mfma_f32_16x16x32_bf16(w, ah1[ks], acc[1][nt], 0, 0, 0);
        }
    }

    // epilogue 1: relu(+b1) -> bf16 hi -> sH (wave's own 32 rows)
    #pragma unroll
    for (int nt = 0; nt < 8; ++nt) {
        const float4 bs = *reinterpret_cast<const float4*>(b1 + nt * 16 + lg * 4);
        #pragma unroll
        for (int mt = 0; mt < 2; ++mt) {
            ushort4 hi;
            hi.x = bf16_rn(fmaxf(acc[mt][nt][0] + bs.x, 0.f));
            hi.y = bf16_rn(fmaxf(acc[mt][nt][1] + bs.y, 0.f));
            hi.z = bf16_rn(fmaxf(acc[mt][nt][2] + bs.z, 0.f));
            hi.w = bf16_rn(fmaxf(acc[mt][nt][3] + bs.w, 0.f));
            *reinterpret_cast<ushort4*>(
                sH + (mW + mt * 16 + lr) * HPAD + nt * 16 + lg * 4) = hi;
        }
    }
    __syncthreads();   // phase-1 sW reads + sH writes complete

    // stage W2 into the same buffer
    #pragma unroll
    for (int i = 0; i < 8; ++i) {
        int g = tid + i * 256;
        *reinterpret_cast<bf16x8*>(sW + (g >> 4) * HPAD + (g & 15) * 8) =
            *reinterpret_cast<const bf16x8*>(W2t + g * 8);
    }
    __syncthreads();

    // ---- phase 2 (normal): A = h1 from LDS, B = W2 from LDS ----
    #pragma unroll
    for (int i = 0; i < 2; ++i)
        #pragma unroll
        for (int j = 0; j < 8; ++j) acc[i][j] = (f32x4){0.f, 0.f, 0.f, 0.f};

    #pragma unroll
    for (int ks = 0; ks < 4; ++ks) {
        const int la0 = (mW + lr) * HPAD + ks * 32 + lg * 8;
        const int la1 = (mW + 16 + lr) * HPAD + ks * 32 + lg * 8;
        bf16x8 xh0 = *reinterpret_cast<const bf16x8*>(sH + la0);
        bf16x8 xh1 = *reinterpret_cast<const bf16x8*>(sH + la1);
        #pragma unroll
        for (int nf = 0; nf < 8; ++nf) {
            bf16x8 w = *reinterpret_cast<const bf16x8*>(
                sW + (nf * 16 + lr) * HPAD + ks * 32 + lg * 8);
            acc[0][nf] = __builtin_amdgcn_mfma_f32_16x16x32_bf16(xh0, w, acc[0][nf], 0, 0, 0);
            acc[1][nf] = __builtin_amdgcn_mfma_f32_16x16x32_bf16(xh1, w, acc[1][nf], 0, 0, 0);
        }
    }

    // epilogue 2: relu(+b2) -> BN -> bf16 hi
    float bs[8], gg[8], bb[8], mm[8], vv[8];
    #pragma unroll
    for (int nf = 0; nf < 8; ++nf) {
        int c = nf * 16 + lr;
        bs[nf] = b2[c];
        gg[nf] = bn_g[c]; bb[nf] = bn_b[c]; mm[nf] = bn_m[c];
        vv[nf] = rsqrtf(bn_v[c] + 1e-5f);
    }
    #pragma unroll
    for (int mr = 0; mr < 2; ++mr) {
        #pragma unroll
        for (int j = 0; j < 4; ++j) {
            int r = m0 + mr * 16 + lg * 4 + j;
            if (r >= N_NODES) continue;
            #pragma unroll
            for (int nf = 0; nf < 8; ++nf) {
                int c = nf * 16 + lr;
                float v = fmaxf(acc[mr][nf][j] + bs[nf], 0.f);
                v = gg[nf] * (v - mm[nf]) * vv[nf] + bb[nf];
                Oh[(size_t)r * HID + c] = bf16_rn(v);
            }
        }
    }
}

// ---------------------------------------------------------------------------
// fused mean-pool + head: one block per graph.
// ---------------------------------------------------------------------------
__device__ __forceinline__ int lbound(const int* __restrict__ a, int n, int key)
{
    int lo = 0, hi = n;
    while (lo < hi) { int mid = (lo + hi) >> 1; if (a[mid] < key) lo = mid + 1; else hi = mid; }
    return lo;
}

__global__ __launch_bounds__(256) void pool_head_kernel(
    const unsigned short* __restrict__ xh, const int* __restrict__ batch,
    const float* __restrict__ w1, const float* __restrict__ b1,
    const float* __restrict__ w2, const float* __restrict__ b2,
    float* __restrict__ out)
{
    __shared__ float s[16][HID];
    __shared__ float p[HID];
    __shared__ float hh[HID];
    __shared__ float lgits[OUT_DIM];
    int g = blockIdx.x;
    int lo = lbound(batch, N_NODES, g);
    int hi = lbound(batch, N_NODES, g + 1);
    int grp = threadIdx.x >> 4, lane = threadIdx.x & 15;

    float a[8];
    #pragma unroll
    for (int j = 0; j < 8; ++j) a[j] = 0.f;
    for (int n = lo + grp; n < hi; n += 16) {
        bf16x8 v = *reinterpret_cast<const bf16x8*>(xh + (size_t)n * HID + lane * 8);
        #pragma unroll
        for (int j = 0; j < 8; ++j) a[j] += bf16_f((unsigned short)v[j]);
    }
    #pragma unroll
    for (int j = 0; j < 8; ++j) s[grp][lane * 8 + j] = a[j];
    __syncthreads();
    if (threadIdx.x < HID) {
        int c = threadIdx.x;
        float sum = 0.f;
        #pragma unroll
        for (int k = 0; k < 16; ++k) sum += s[k][c];
        float cnt = (float)(hi - lo);
        if (cnt < 1.f) cnt = 1.f;
        p[c] = sum / cnt;
    }
    __syncthreads();

    int j = threadIdx.x;
    if (j < HID) {
        float acc = b1[j];
        #pragma unroll 8
        for (int k = 0; k < HID; ++k) acc = fmaf(p[k], w1[k * HID + j], acc);
        hh[j] = fmaxf(acc, 0.f);
    }
    __syncthreads();

    if (j < OUT_DIM) {
        float acc = b2[j];
        #pragma unroll 8
        for (int k = 0; k < HID; ++k) acc = fmaf(hh[k], w2[k * OUT_DIM + j], acc);
        lgits[j] = acc;
    }
    __syncthreads();

    if (j == 0) {
        float mx = lgits[0];
        for (int o = 1; o < OUT_DIM; ++o) mx = fmaxf(mx, lgits[o]);
        float sum = 0.f;
        for (int o = 0; o < OUT_DIM; ++o) sum += expf(lgits[o] - mx);
        float lse = mx + logf(sum);
        for (int o = 0; o < OUT_DIM; ++o) out[g * OUT_DIM + o] = lgits[o] - lse;
    }
}

// ---------------------------------------------------------------------------
extern "C" void kernel_launch(void* const* d_in, const int* in_sizes, int n_in,
                              void* d_out, int out_size, void* d_ws, size_t ws_size,
                              hipStream_t stream)
{
    const float* x     = (const float*)d_in[0];
    const int*   ei    = (const int*)d_in[1];
    const int*   batch = (const int*)d_in[2];
    const float* W1    = (const float*)d_in[3];
    const float* b1    = (const float*)d_in[4];
    const float* W2    = (const float*)d_in[5];
    const float* b2    = (const float*)d_in[6];
    const float* bng   = (const float*)d_in[7];
    const float* bnb   = (const float*)d_in[8];
    const float* bnm   = (const float*)d_in[9];
    const float* bnv   = (const float*)d_in[10];
    const float* epsg  = (const float*)d_in[11];
    const float* l1w   = (const float*)d_in[12];
    const float* l1b   = (const float*)d_in[13];
    const float* l2w   = (const float*)d_in[14];
    const float* l2b   = (const float*)d_in[15];
    float* out = (float*)d_out;

    const int* src = ei;
    const int* dst = ei + N_EDGES;

    const size_t NF = (size_t)N_NODES * HID;     // 6.4M
    unsigned char* p = (unsigned char*)d_ws;
    unsigned short* xhA = (unsigned short*)p; p += NF * 2;
    unsigned short* xhB = (unsigned short*)p; p += NF * 2;
    unsigned short* h0h = (unsigned short*)p; p += NF * 2;
    unsigned short* Wth = (unsigned short*)p; p += (size_t)8 * HID * HID * 2;
    int* rowptr = (int*)p;                p += (size_t)(N_NODES + 1) * 4;
    int* bukCnt = (int*)p;                p += NBUK * 4;
    unsigned int* bucketData = (unsigned int*)p; p += (size_t)NBUK * BUK_STRIDE * 4;
    int* csr    = (int*)p;

    // ---- prep (once per call): conv_x + conv_weights + bukCnt zero ----
    prep_kernel<<<CONVX_BLOCKS + CONVW_BLOCKS, 256, 0, stream>>>(
        x, xhA, W1, W2, Wth, bukCnt);
    bin_kernel<<<NBUK, 256, 0, stream>>>(src, dst, bukCnt, bucketData);
    build_kernel<<<NBUK, 256, 0, stream>>>(bukCnt, bucketData, rowptr, csr);

    // ---- 4 GIN layers ----
    const int aggBlocks = (N_NODES + 15) / 16;     // 3125
    const int mlpBlocks = (N_NODES + 127) / 128;   // 391

    unsigned short* cur = xhA;
    unsigned short* nxt = xhB;
    for (int l = 0; l < 4; ++l) {
        aggregate_kernel<<<aggBlocks, 256, 0, stream>>>(
            cur, rowptr, csr, epsg + l, h0h);
        mlp_fused<<<mlpBlocks, 256, 0, stream>>>(
            h0h,
            Wth + (size_t)l * HID * HID, b1 + l * HID,
            Wth + (size_t)(4 + l) * HID * HID, b2 + l * HID,
            bng + l * HID, bnb + l * HID, bnm + l * HID, bnv + l * HID,
            nxt);
        unsigned short* t = cur; cur = nxt; nxt = t;
    }

    // ---- fused pool + head ----
    pool_head_kernel<<<N_GRAPHS, 256, 0, stream>>>(
        cur, batch, l1w, l1b, l2w, l2b, out);
}